// Round 5
// baseline (3613.110 us; speedup 1.0000x reference)
//
#include <hip/hip_runtime.h>
#include <cstdint>
#include <cstddef>

#define N_ROWS 16384
#define CDIM_C 512
#define HDIM_C 1024
#define FDIM_C 512
#define KMIX 5

typedef unsigned short u16;
typedef __attribute__((ext_vector_type(8))) short bf16x8;
typedef __attribute__((ext_vector_type(4))) float f32x4;

__device__ __forceinline__ u16 f2bf(float x) {
  unsigned u = __float_as_uint(x);
  unsigned r = (u + 0x7fffu + ((u >> 16) & 1u)) >> 16;
  return (u16)r;
}
__device__ __forceinline__ float bf2f(u16 h) {
  return __uint_as_float(((unsigned)h) << 16);
}

__device__ __forceinline__ void gload_lds16(const u16* g, u16* l) {
  __builtin_amdgcn_global_load_lds((const __attribute__((address_space(1))) void*)g,
                                   (__attribute__((address_space(3))) void*)l,
                                   16, 0, 0);
}

// ---------------------------------------------------------------------------
// split c (3-way bf16 Dekker split, exact 24-bit capture)
// ---------------------------------------------------------------------------
__global__ void split3_kernel(const float* __restrict__ x, u16* __restrict__ P0,
                              u16* __restrict__ P1, u16* __restrict__ P2, size_t n) {
  for (size_t i = (size_t)blockIdx.x * 256 + threadIdx.x; i < n; i += (size_t)gridDim.x * 256) {
    const float v = x[i];
    const u16 h = f2bf(v); const float hf = bf2f(h);
    const u16 m = f2bf(v - hf); const float mf = bf2f(m);
    P0[i] = h; P1[i] = m; P2[i] = f2bf(v - hf - mf);
  }
}

// ---------------------------------------------------------------------------
// transpose W[R][C] -> planes [C][R] with 2- or 3-way split.
// PERM: interleave mean/logvar columns (c<512 -> 2c, c>=512 -> 2(c-512)+1)
// ---------------------------------------------------------------------------
template <int NP, bool PERM>
__global__ void transp_split_kernel(const float* __restrict__ W, u16* __restrict__ P0,
                                    u16* __restrict__ P1, u16* __restrict__ P2,
                                    int R, int C) {
  __shared__ float t[32][33];
  const int bz = blockIdx.z;
  const float* Wz = W + (size_t)bz * R * C;
  const size_t oofs = (size_t)bz * R * C;
  const int r0 = blockIdx.x * 32, c0 = blockIdx.y * 32;
  const int tx = threadIdx.x, ty = threadIdx.y;  // (32,8)
#pragma unroll
  for (int i = 0; i < 4; ++i)
    t[ty + i * 8][tx] = Wz[(size_t)(r0 + ty + i * 8) * C + c0 + tx];
  __syncthreads();
#pragma unroll
  for (int i = 0; i < 4; ++i) {
    const int c_raw = c0 + ty + i * 8, r = r0 + tx;
    const int c = PERM ? ((c_raw < FDIM_C) ? (c_raw * 2) : ((c_raw - FDIM_C) * 2 + 1)) : c_raw;
    const float x = t[tx][ty + i * 8];
    const size_t idx = oofs + (size_t)c * R + r;
    const u16 h = f2bf(x);
    P0[idx] = h;
    const float hf = bf2f(h);
    const u16 m = f2bf(x - hf);
    P1[idx] = m;
    if (NP >= 3) {
      const float mf = bf2f(m);
      P2[idx] = f2bf(x - hf - mf);
    }
  }
}

// ---------------------------------------------------------------------------
// 128x128-tile stacked-K' MFMA GEMM (m97-structure: single-buffered LDS,
// __syncthreads pair per K-step). BK=64, 4 waves (2x2), 4x4 fragments/wave.
// C[M][1024] = sum_seg A_{TA[seg]} @ B_{TB[seg]}^T  (planes stacked along K')
// LDS 32KB -> 4 wgs/CU with __launch_bounds__(256,4): all 1024 wgs resident.
// MIX: fused sample+mixture epilogue (gw2 cols pre-permuted; pairs via shfl).
// ---------------------------------------------------------------------------
template <int NT, bool RELU, int OSPL, int MIX, int BPC>
__global__ __launch_bounds__(256, BPC) void gemm128(
    const u16* __restrict__ A0, const u16* __restrict__ A1, const u16* __restrict__ A2,
    const u16* __restrict__ B0, const u16* __restrict__ B1, const u16* __restrict__ B2,
    const float* __restrict__ bias, float* __restrict__ outF,
    u16* __restrict__ O0, u16* __restrict__ O1, u16* __restrict__ O2,
    const float* __restrict__ noise_k, const float* __restrict__ wvec,
    float* __restrict__ mixout, int kidx,
    int Kd, int kpsl, int nsteps) {
  __shared__ __align__(16) u16 lds[16384];  // A:[8kb][128r][8] @0, B same @8192 (32 KiB)
  const int tid = threadIdx.x;
  const int lane = tid & 63;
  const int wave = tid >> 6;
  const int wm = wave >> 1, wn = wave & 1;
  const int hi4 = lane >> 4, rl = lane & 15;
  const int kmask = (1 << kpsl) - 1;

  // bijective XCD swizzle (nwg = 1024, divisible by 8)
  const int nwg = (int)(gridDim.x * gridDim.y);
  const int orig = (int)(blockIdx.y * gridDim.x + blockIdx.x);
  const int cpx = nwg >> 3;
  const int wg = (orig & 7) * cpx + (orig >> 3);
  const int col0 = (wg & 7) * 128;
  const int row0 = (wg >> 3) * 128;

  f32x4 acc[4][4] = {};

  for (int kt = 0; kt < nsteps; ++kt) {
    const int seg = kt >> kpsl;
    const int ko = (kt & kmask) << 6;
    const u16 *pa, *pb;
    if constexpr (NT == 3) {  // TA=[0,0,1] TB=[0,1,0]
      pa = (seg == 2) ? A1 : A0;
      pb = (seg == 1) ? B1 : B0;
    } else {                  // NT==6: TA=[0,0,1,1,0,2] TB=[0,1,0,1,2,0]
      pa = (seg == 2 || seg == 3) ? A1 : ((seg == 5) ? A2 : A0);
      pb = (seg == 1 || seg == 3) ? B1 : ((seg == 4) ? B2 : B0);
    }

    __syncthreads();  // previous step's reads done before overwrite
#pragma unroll
    for (int it = 0; it < 4; ++it) {
      const int sbase = it * 256 + (wave << 6);  // wave-uniform slot base
      const int slot = sbase + lane;
      const int skb = slot >> 7, sr = slot & 127;
      gload_lds16(pa + (size_t)(row0 + sr) * Kd + ko + skb * 8, &lds[sbase * 8]);
      gload_lds16(pb + (size_t)(col0 + sr) * Kd + ko + skb * 8, &lds[8192 + sbase * 8]);
    }
    __syncthreads();  // compiler emits vmcnt(0) drain: staged tile visible

#pragma unroll
    for (int ks = 0; ks < 2; ++ks) {
      bf16x8 aR[4], bR[4];
      const int kb = ks * 4 + hi4;
#pragma unroll
      for (int i = 0; i < 4; ++i)
        aR[i] = *(const bf16x8*)&lds[kb * 1024 + (wm * 64 + i * 16 + rl) * 8];
#pragma unroll
      for (int j = 0; j < 4; ++j)
        bR[j] = *(const bf16x8*)&lds[8192 + kb * 1024 + (wn * 64 + j * 16 + rl) * 8];
#pragma unroll
      for (int i = 0; i < 4; ++i)
#pragma unroll
        for (int j = 0; j < 4; ++j)
          acc[i][j] = __builtin_amdgcn_mfma_f32_16x16x32_bf16(aR[i], bR[j], acc[i][j], 0, 0, 0);
    }
  }

  // epilogue: D layout col = lane&15, row = (lane>>4)*4 + r  [m89/m91 verified]
#pragma unroll
  for (int i = 0; i < 4; ++i)
#pragma unroll
    for (int j = 0; j < 4; ++j)
#pragma unroll
      for (int r = 0; r < 4; ++r) {
        const int row = row0 + wm * 64 + i * 16 + hi4 * 4 + r;
        const int col = col0 + wn * 64 + j * 16 + rl;
        if constexpr (MIX > 0) {
          // permuted cols: even = mean_f, odd = logvar_f, f = col>>1
          const int f = col >> 1;
          const int ocol = (col & 1) ? (f + FDIM_C) : f;
          const float y = acc[i][j][r] + bias[ocol];
          const float other = __shfl_xor(y, 1);
          if (!(lane & 1)) {
            const float sample = y + noise_k[(size_t)row * FDIM_C + f] * expf(0.5f * other);
            const float v = wvec[row * KMIX + kidx] * sample;
            float* op = &mixout[(size_t)row * FDIM_C + f];
            if constexpr (MIX == 1) *op = v; else *op += v;
          }
        } else {
          float y = acc[i][j][r] + bias[col];
          if (RELU) y = fmaxf(y, 0.0f);
          const size_t idx = (size_t)row * HDIM_C + col;
          if constexpr (OSPL == 0) {
            outF[idx] = y;
          } else {
            const u16 h = f2bf(y);
            const float hf = bf2f(h);
            const u16 m = f2bf(y - hf);
            O0[idx] = h;
            O1[idx] = m;
            if constexpr (OSPL == 3) {
              const float mf = bf2f(m);
              O2[idx] = f2bf(y - hf - mf);
            }
          }
        }
      }
}

// ---------------------------------------------------------------------------
// logits = h2 @ pw2 + pb2 ; softmax ; gumbel ; argmax ; mixture weights
// one wave per row, fp64 accumulation (argmax flip protection)
// ---------------------------------------------------------------------------
__global__ void p2_weights_kernel(const float* __restrict__ h2, const float* __restrict__ pw2,
                                  const float* __restrict__ pb2, const float* __restrict__ gu,
                                  float* __restrict__ w) {
  const int n = blockIdx.x * 4 + (threadIdx.x >> 6);
  const int lane = threadIdx.x & 63;
  const float* hrow = h2 + (size_t)n * HDIM_C;
  double acc[KMIX] = {0, 0, 0, 0, 0};
  const int c0 = lane * 16;
#pragma unroll
  for (int jj = 0; jj < 16; ++jj) {
    const int cc = c0 + jj;
    const double hv = (double)hrow[cc];
#pragma unroll
    for (int kk = 0; kk < KMIX; ++kk)
      acc[kk] += hv * (double)pw2[cc * KMIX + kk];
  }
#pragma unroll
  for (int offs = 32; offs >= 1; offs >>= 1)
#pragma unroll
    for (int kk = 0; kk < KMIX; ++kk)
      acc[kk] += __shfl_down(acc[kk], offs);
  if (lane == 0) {
    double lg[KMIX], mx = -1e300;
#pragma unroll
    for (int kk = 0; kk < KMIX; ++kk) {
      lg[kk] = acc[kk] + (double)pb2[kk];
      if (lg[kk] > mx) mx = lg[kk];
    }
    double e[KMIX], s = 0.0;
#pragma unroll
    for (int kk = 0; kk < KMIX; ++kk) { e[kk] = exp(lg[kk] - mx); s += e[kk]; }
    int idx = 0; double zb = -1e300;
#pragma unroll
    for (int kk = 0; kk < KMIX; ++kk) {
      const double ps = e[kk] / s;
      const double u = (double)gu[n * KMIX + kk];
      const double g = -log(-log(u + 1e-20) + 1e-20);
      const double zz = log(ps + 1e-20) + g;
      if (zz > zb) { zb = zz; idx = kk; }  // strict > keeps first index (jnp.argmax)
    }
#pragma unroll
    for (int kk = 0; kk < KMIX; ++kk)
      w[n * KMIX + kk] = (float)((e[kk] / s + (kk == idx ? 5.0 : 0.0)) / 6.0);
  }
}

// ---------------------------------------------------------------------------
extern "C" void kernel_launch(void* const* d_in, const int* in_sizes, int n_in,
                              void* d_out, int out_size, void* d_ws, size_t ws_size,
                              hipStream_t stream) {
  const float* c   = (const float*)d_in[0];
  const float* noise = (const float*)d_in[2];
  const float* gu  = (const float*)d_in[3];
  const float* pw0 = (const float*)d_in[4];
  const float* pb0 = (const float*)d_in[5];
  const float* pw1 = (const float*)d_in[6];
  const float* pb1 = (const float*)d_in[7];
  const float* pw2 = (const float*)d_in[8];
  const float* pb2 = (const float*)d_in[9];
  const float* gw0 = (const float*)d_in[10];
  const float* gb0 = (const float*)d_in[11];
  const float* gw1 = (const float*)d_in[12];
  const float* gb1 = (const float*)d_in[13];
  const float* gw2 = (const float*)d_in[14];
  const float* gb2 = (const float*)d_in[15];
  float* out = (float*)d_out;

  char* ws = (char*)d_ws;
  size_t off = 0;
  auto alloc = [&](size_t bytes) -> char* {
    off = (off + 255) & ~(size_t)255;
    char* p = ws + off;
    off += bytes;
    return p;
  };

  const size_t NCp = (size_t)N_ROWS * CDIM_C * 2;
  const size_t NHp = (size_t)N_ROWS * HDIM_C * 2;
  u16* cH = (u16*)alloc(NCp);
  u16* cM = (u16*)alloc(NCp);
  u16* cL = (u16*)alloc(NCp);
  u16* pw0T0 = (u16*)alloc((size_t)CDIM_C * HDIM_C * 2);
  u16* pw0T1 = (u16*)alloc((size_t)CDIM_C * HDIM_C * 2);
  u16* pw0T2 = (u16*)alloc((size_t)CDIM_C * HDIM_C * 2);
  u16* pw1T0 = (u16*)alloc((size_t)HDIM_C * HDIM_C * 2);
  u16* pw1T1 = (u16*)alloc((size_t)HDIM_C * HDIM_C * 2);
  u16* pw1T2 = (u16*)alloc((size_t)HDIM_C * HDIM_C * 2);
  u16* hH = (u16*)alloc(NHp);
  u16* hM = (u16*)alloc(NHp);
  u16* hL = (u16*)alloc(NHp);
  float* h2 = (float*)alloc((size_t)N_ROWS * HDIM_C * 4);
  float* wbuf = (float*)alloc((size_t)N_ROWS * KMIX * 4);
  u16* gw0T0 = (u16*)alloc((size_t)KMIX * CDIM_C * HDIM_C * 2);
  u16* gw0T1 = (u16*)alloc((size_t)KMIX * CDIM_C * HDIM_C * 2);
  u16* gw1T0 = (u16*)alloc((size_t)KMIX * HDIM_C * HDIM_C * 2);
  u16* gw1T1 = (u16*)alloc((size_t)KMIX * HDIM_C * HDIM_C * 2);
  u16* gw2T0 = (u16*)alloc((size_t)KMIX * HDIM_C * HDIM_C * 2);
  u16* gw2T1 = (u16*)alloc((size_t)KMIX * HDIM_C * HDIM_C * 2);
  u16* g2b = (u16*)alloc(NHp);
  u16* g1a = hH;   // h planes dead after P1
  u16* g1b = hM;
  u16* g2a = hL;
  (void)ws_size; (void)in_sizes; (void)n_in; (void)out_size;

  // ---- prep ----
  split3_kernel<<<2048, 256, 0, stream>>>(c, cH, cM, cL, (size_t)N_ROWS * CDIM_C);
  transp_split_kernel<3, false><<<dim3(CDIM_C / 32, HDIM_C / 32, 1), dim3(32, 8), 0, stream>>>(
      pw0, pw0T0, pw0T1, pw0T2, CDIM_C, HDIM_C);
  transp_split_kernel<3, false><<<dim3(HDIM_C / 32, HDIM_C / 32, 1), dim3(32, 8), 0, stream>>>(
      pw1, pw1T0, pw1T1, pw1T2, HDIM_C, HDIM_C);
  transp_split_kernel<2, false><<<dim3(CDIM_C / 32, HDIM_C / 32, KMIX), dim3(32, 8), 0, stream>>>(
      gw0, gw0T0, gw0T1, nullptr, CDIM_C, HDIM_C);
  transp_split_kernel<2, false><<<dim3(HDIM_C / 32, HDIM_C / 32, KMIX), dim3(32, 8), 0, stream>>>(
      gw1, gw1T0, gw1T1, nullptr, HDIM_C, HDIM_C);
  transp_split_kernel<2, true><<<dim3(HDIM_C / 32, HDIM_C / 32, KMIX), dim3(32, 8), 0, stream>>>(
      gw2, gw2T0, gw2T1, nullptr, HDIM_C, HDIM_C);

  const dim3 gg(HDIM_C / 128, N_ROWS / 128);  // (8, 128) = 1024 wgs

  // ---- P network (6-term stacked K', ~fp32-exact for argmax safety) ----
  gemm128<6, true, 3, 0, 4><<<gg, 256, 0, stream>>>(
      cH, cM, cL, pw0T0, pw0T1, pw0T2, pb0, nullptr, hH, hM, hL,
      nullptr, nullptr, nullptr, 0, CDIM_C, 3, 48);
  gemm128<6, true, 0, 0, 4><<<gg, 256, 0, stream>>>(
      hH, hM, hL, pw1T0, pw1T1, pw1T2, pb1, h2, nullptr, nullptr, nullptr,
      nullptr, nullptr, nullptr, 0, HDIM_C, 4, 96);
  p2_weights_kernel<<<N_ROWS / 4, 256, 0, stream>>>(h2, pw2, pb2, gu, wbuf);

  // ---- G network (3-term stacked K') + fused mix epilogue ----
  for (int k = 0; k < KMIX; ++k) {
    gemm128<3, true, 2, 0, 4><<<gg, 256, 0, stream>>>(
        cH, cM, nullptr,
        gw0T0 + (size_t)k * CDIM_C * HDIM_C, gw0T1 + (size_t)k * CDIM_C * HDIM_C, nullptr,
        gb0 + k * HDIM_C, nullptr, g1a, g1b, nullptr,
        nullptr, nullptr, nullptr, 0, CDIM_C, 3, 24);
    gemm128<3, true, 2, 0, 4><<<gg, 256, 0, stream>>>(
        g1a, g1b, nullptr,
        gw1T0 + (size_t)k * HDIM_C * HDIM_C, gw1T1 + (size_t)k * HDIM_C * HDIM_C, nullptr,
        gb1 + k * HDIM_C, nullptr, g2a, g2b, nullptr,
        nullptr, nullptr, nullptr, 0, HDIM_C, 4, 48);
    if (k == 0)
      gemm128<3, false, 0, 1, 4><<<gg, 256, 0, stream>>>(
          g2a, g2b, nullptr,
          gw2T0 + (size_t)k * HDIM_C * HDIM_C, gw2T1 + (size_t)k * HDIM_C * HDIM_C, nullptr,
          gb2 + k * HDIM_C, nullptr, nullptr, nullptr, nullptr,
          noise + (size_t)k * N_ROWS * FDIM_C, wbuf, out, k, HDIM_C, 4, 48);
    else
      gemm128<3, false, 0, 2, 4><<<gg, 256, 0, stream>>>(
          g2a, g2b, nullptr,
          gw2T0 + (size_t)k * HDIM_C * HDIM_C, gw2T1 + (size_t)k * HDIM_C * HDIM_C, nullptr,
          gb2 + k * HDIM_C, nullptr, nullptr, nullptr, nullptr,
          noise + (size_t)k * N_ROWS * FDIM_C, wbuf, out, k, HDIM_C, 4, 48);
  }
}